// Round 7
// baseline (248.153 us; speedup 1.0000x reference)
//
#include <hip/hip_runtime.h>

typedef __attribute__((ext_vector_type(8))) __bf16 bf16x8;
typedef __attribute__((ext_vector_type(4))) float floatx4;

#define M_TOT 256
#define K_TOT 5120
#define N_TOT 13824
#define NBLK  320      // K/16
#define BN    128
#define KSPLIT 4
#define KCH   1280     // K / KSPLIT
#define KSUP  256      // K per LDS A-chunk
#define NSUP  5        // KCH / KSUP

#define GLOAD_LDS16(g, l)                                                     \
  __builtin_amdgcn_global_load_lds(                                           \
      (const __attribute__((address_space(1))) void*)(g),                     \
      (__attribute__((address_space(3))) void*)(l), 16, 0, 0)

static __device__ __forceinline__ float bf16r(float v) { return (float)(__bf16)v; }

static __device__ __forceinline__ float fp4round(float v) {
  float a = fabsf(v), q;
  if      (a < 0.25f) q = 0.0f;
  else if (a < 0.75f) q = 0.5f;
  else if (a < 1.25f) q = 1.0f;
  else if (a < 1.75f) q = 1.5f;
  else if (a < 2.5f)  q = 2.0f;
  else if (a < 3.5f)  q = 3.0f;
  else if (a < 5.0f)  q = 4.0f;
  else                q = 6.0f;
  return copysignf(q, v);
}

// round f (in [0,448]) to fp8 e4m3fn, RNE — exact pow2 arithmetic
static __device__ __forceinline__ float cvt_e4m3(float f) {
  if (f < 0.015625f) return rintf(f * 512.0f) * 0.001953125f;  // subnormal, q=2^-9
  int e = (int)(__float_as_uint(f) >> 23) - 127;
  float q = __uint_as_float((unsigned)(e - 3 + 127) << 23);    // 2^(e-3)
  return rintf(f / q) * q;                                     // exact div/mul by pow2
}

// ------- kernel 1: zero output (atomic target) + global amax of bf16(x) -------
__global__ void k_prep(const float* __restrict__ x, unsigned* __restrict__ amax_bits,
                       float4* __restrict__ out4) {
  int idx = blockIdx.x * blockDim.x + threadIdx.x;   // 327680 threads
#pragma unroll 1
  for (int j = idx; j < 884736; j += 327680) out4[j] = (float4){0.f, 0.f, 0.f, 0.f};
  float4 v = ((const float4*)x)[idx];                // exact cover of x
  float m = fmaxf(fmaxf(fabsf(bf16r(v.x)), fabsf(bf16r(v.y))),
                  fmaxf(fabsf(bf16r(v.z)), fabsf(bf16r(v.w))));
#pragma unroll
  for (int off = 32; off; off >>= 1) m = fmaxf(m, __shfl_xor(m, off));
  if ((threadIdx.x & 63) == 0) atomicMax(amax_bits, __float_as_uint(m));
}

// ------- kernel 2: activation nvfp4 quant, folded to bf16 a_u = q*s -------
__global__ void k_aquant(const float* __restrict__ x,
                         const unsigned* __restrict__ amax_bits,
                         __bf16* __restrict__ au) {
  int idx = blockIdx.x * blockDim.x + threadIdx.x;  // 0..81919 (m*320+b)
  int m = idx / NBLK;
  int b = idx - m * NBLK;
  float amax = __uint_as_float(*amax_bits);
  float gs  = 2688.0f / amax;   // (448*6)/amax, matches ref op order
  float gs6 = gs / 6.0f;
  const float4* xp = (const float4*)(x + m * K_TOT + b * 16);
  float4 v0 = xp[0], v1 = xp[1], v2 = xp[2], v3 = xp[3];
  float xv[16];
  xv[0]=bf16r(v0.x); xv[1]=bf16r(v0.y); xv[2]=bf16r(v0.z); xv[3]=bf16r(v0.w);
  xv[4]=bf16r(v1.x); xv[5]=bf16r(v1.y); xv[6]=bf16r(v1.z); xv[7]=bf16r(v1.w);
  xv[8]=bf16r(v2.x); xv[9]=bf16r(v2.y); xv[10]=bf16r(v2.z); xv[11]=bf16r(v2.w);
  xv[12]=bf16r(v3.x); xv[13]=bf16r(v3.y); xv[14]=bf16r(v3.z); xv[15]=bf16r(v3.w);
  float am = 0.f;
#pragma unroll
  for (int j = 0; j < 16; ++j) am = fmaxf(am, fabsf(xv[j]));
  float s = cvt_e4m3(fminf(am * gs6, 448.0f));
  float g = gs / ((s == 0.f) ? 1.f : s);
  bf16x8 p0, p1;
#pragma unroll
  for (int j = 0; j < 8; ++j) p0[j] = (__bf16)(fp4round(xv[j] * g) * s);      // exact in bf16
#pragma unroll
  for (int j = 0; j < 8; ++j) p1[j] = (__bf16)(fp4round(xv[8 + j] * g) * s);
  bf16x8* dst = (bf16x8*)(au + (size_t)idx * 16);
  dst[0] = p0; dst[1] = p1;
}

// -------- kernel 3: wave-decoupled GEMM: A one-shot in LDS, W streamed to regs --------
// BM=256 (all M), BN=128, 1024 thr = 16 waves (2m x 8n), wave tile 128x16.
// A: 256x256 bf16 chunk (128 KB LDS) staged once per super-step (2 barriers each).
// W: per-wave register ring (depth 2 x 64-K), compiler-counted vmcnt, NO barriers.
// Order discipline: A gloads pinned OLDEST via sched_barrier; vmcnt(8) then
// retires all 8 A loads regardless of how many VMEM instrs the W path became.
__global__ __launch_bounds__(1024, 4) void k_gemm(
    const __bf16* __restrict__ au,      // [256][5120] bf16 (scales folded)
    const float*  __restrict__ w,       // [N][K] fp4 values in f32
    const float*  __restrict__ wsc,     // [N][320] fp8-representable scales
    const unsigned* __restrict__ amax_bits,
    const float*  __restrict__ wgs,     // scalar
    const float*  __restrict__ bias,    // [N]
    float* __restrict__ out)            // [256][13824], pre-zeroed
{
  __shared__ __bf16 Ab[M_TOT * KSUP];   // 128 KB

  const int tid  = threadIdx.x;
  const int lane = tid & 63;
  const int wv   = tid >> 6;     // 0..15
  const int wm   = wv >> 3;      // 0..1 (128-row half)
  const int wn   = wv & 7;       // 0..7 (16-col slab)

  const int s     = blockIdx.x & 3;          // XCD-fixed under round-robin dispatch
  const int n0    = (blockIdx.x >> 2) * BN;
  const int kbase = s * KCH;

  const int hi  = lane >> 4;     // 0..3
  const int r15 = lane & 15;
  const int xo  = r15 & 7;

  // A staging (gload_lds, linear dest): LDS row = 512B; 16B chunk c of row r
  // stored at slot c ^ (r&7); achieved by pre-swizzling the global column.
  const int arow0 = tid >> 5;                         // + i*32
  const int achk  = (tid & 31) ^ ((tid >> 5) & 7);    // logical chunk for this thread
  const __bf16* asrc0 = au + (size_t)arow0 * K_TOT + kbase + achk * 8;

  // W per-lane pointers: lane (r15,hi) owns row n0+wn*16+r15, k-cols hi*8..+8
  const int nrow = n0 + wn * 16 + r15;
  const float* wrow  = w   + (size_t)nrow * K_TOT + kbase + hi * 8;
  const float* wsrow = wsc + (size_t)nrow * NBLK + s * (KCH / 16);
  const int hi2 = hi >> 1;

  // A fragment read offsets: byte = (wm*128+fm*16+r15)*512 + j*128 + cof[ks]
  const int abase = (wm * 128 + r15) * 512;
  const int cof0  = ((0 * 4 + hi) ^ xo) << 4;
  const int cof1  = ((1 * 4 + hi) ^ xo) << 4;

  floatx4 acc[8];
#pragma unroll
  for (int fm = 0; fm < 8; ++fm) acc[fm] = (floatx4){0.f, 0.f, 0.f, 0.f};

  struct WSlot { float4 a, b, c, d; float s0, s1; };
  WSlot sA, sB;

  auto issueA = [&](int c) {
    const __bf16* src = asrc0 + c * KSUP;
    char* dst = (char*)Ab + tid * 16;
#pragma unroll
    for (int i = 0; i < 8; ++i)
      GLOAD_LDS16(src + (size_t)i * 32 * K_TOT, dst + i * 16384);
  };
  auto issueW = [&](WSlot& sl, int t) {    // t = global 64-K step index
    const float* p = wrow + t * 64;
    sl.a = *(const float4*)(p);
    sl.b = *(const float4*)(p + 4);
    sl.c = *(const float4*)(p + 32);
    sl.d = *(const float4*)(p + 36);
    sl.s0 = wsrow[t * 4 + hi2];
    sl.s1 = wsrow[t * 4 + 2 + hi2];
  };
  auto cvt8 = [](float4 x, float4 y, float sc) {
    bf16x8 r;
    r[0] = (__bf16)(x.x * sc); r[1] = (__bf16)(x.y * sc);
    r[2] = (__bf16)(x.z * sc); r[3] = (__bf16)(x.w * sc);
    r[4] = (__bf16)(y.x * sc); r[5] = (__bf16)(y.y * sc);
    r[6] = (__bf16)(y.z * sc); r[7] = (__bf16)(y.w * sc);   // exact in bf16
    return r;
  };
  auto stepC = [&](WSlot& sl, int j, int tre) {
    bf16x8 b0 = cvt8(sl.a, sl.b, sl.s0);   // compiler inserts counted vmcnt here
    bf16x8 b1 = cvt8(sl.c, sl.d, sl.s1);
    if (tre >= 0) issueW(sl, tre);         // reissue slot for step j+2
    const char* pA = (const char*)Ab + abase + j * 128;
#pragma unroll
    for (int fm = 0; fm < 8; ++fm) {
      bf16x8 af = *(const bf16x8*)(pA + fm * 8192 + cof0);
      acc[fm] = __builtin_amdgcn_mfma_f32_16x16x32_bf16(af, b0, acc[fm], 0, 0, 0);
    }
#pragma unroll
    for (int fm = 0; fm < 8; ++fm) {
      bf16x8 af = *(const bf16x8*)(pA + fm * 8192 + cof1);
      acc[fm] = __builtin_amdgcn_mfma_f32_16x16x32_bf16(af, b1, acc[fm], 0, 0, 0);
    }
  };

#pragma unroll 1
  for (int c = 0; c < NSUP; ++c) {
    const int tb = c * 4;
    if (c > 0) {
      // all waves done READING previous A-chunk
      asm volatile("s_waitcnt lgkmcnt(0)" ::: "memory");
      __builtin_amdgcn_sched_barrier(0);
      __builtin_amdgcn_s_barrier();
      __builtin_amdgcn_sched_barrier(0);
    }
    issueA(c);                 // 8 gload_lds — pinned OLDEST in the VMEM FIFO
    __builtin_amdgcn_sched_barrier(0);
    issueW(sA, tb + 0);        // W loads strictly after A in issue order
    issueW(sB, tb + 1);
    asm volatile("s_waitcnt vmcnt(8)" ::: "memory");   // retires ALL 8 A loads
    __builtin_amdgcn_sched_barrier(0);
    __builtin_amdgcn_s_barrier();
    __builtin_amdgcn_sched_barrier(0);
    // 4 x 64-K steps, barrier-free, per-wave pipelined
    stepC(sA, 0, tb + 2);
    stepC(sB, 1, tb + 3);
    stepC(sA, 2, -1);
    stepC(sB, 3, -1);
  }

  // epilogue: atomic accumulate (out pre-zeroed; bias folded into split 0)
  float amax = __uint_as_float(*amax_bits);
  float a_gs = 2688.0f / amax;
  float alpha = 1.0f / (a_gs * wgs[0]);
  const int ncol = n0 + wn * 16 + r15;
  const float bb = (s == 0) ? bias[ncol] : 0.0f;
#pragma unroll
  for (int fm = 0; fm < 8; ++fm) {
    int mrow = wm * 128 + fm * 16 + hi * 4;
#pragma unroll
    for (int j = 0; j < 4; ++j)
      atomicAdd(&out[(size_t)(mrow + j) * N_TOT + ncol],
                acc[fm][j] * alpha + bb);
  }
}

extern "C" void kernel_launch(void* const* d_in, const int* in_sizes, int n_in,
                              void* d_out, int out_size, void* d_ws, size_t ws_size,
                              hipStream_t stream) {
  const float* x    = (const float*)d_in[0];
  const float* wq   = (const float*)d_in[1];
  const float* wsc  = (const float*)d_in[2];
  const float* wgs  = (const float*)d_in[3];
  const float* bias = (const float*)d_in[4];
  float* out = (float*)d_out;

  unsigned* amax = (unsigned*)d_ws;
  __bf16* au = (__bf16*)((char*)d_ws + 256);   // 2.62 MB scratch

  hipMemsetAsync(d_ws, 0, 4, stream);
  k_prep<<<dim3(1280), dim3(256), 0, stream>>>(x, amax, (float4*)out);
  k_aquant<<<dim3(M_TOT * NBLK / 256), dim3(256), 0, stream>>>(x, amax, au);
  k_gemm<<<dim3((N_TOT / BN) * KSPLIT), dim3(1024), 0, stream>>>(au, wq, wsc, amax, wgs, bias, out);
}

// Round 8
// 223.708 us; speedup vs baseline: 1.1093x; 1.1093x over previous
//
#include <hip/hip_runtime.h>

typedef __attribute__((ext_vector_type(8))) __bf16 bf16x8;
typedef __attribute__((ext_vector_type(4))) float floatx4;

#define M_TOT 256
#define K_TOT 5120
#define N_TOT 13824
#define NBLK  320      // K/16
#define BN    64
#define BK    64
#define KSPLIT 4
#define KCH   1280     // K / KSPLIT
#define NSTEP 20       // KCH / BK
#define KPACK (K_TOT/8)   // 640 u32 per row

#define GLOAD_LDS16(g, l)                                                     \
  __builtin_amdgcn_global_load_lds(                                           \
      (const __attribute__((address_space(1))) void*)(g),                     \
      (__attribute__((address_space(3))) void*)(l), 16, 0, 0)

static __device__ __forceinline__ float bf16r(float v) { return (float)(__bf16)v; }

static __device__ __forceinline__ float fp4round(float v) {
  float a = fabsf(v), q;
  if      (a < 0.25f) q = 0.0f;
  else if (a < 0.75f) q = 0.5f;
  else if (a < 1.25f) q = 1.0f;
  else if (a < 1.75f) q = 1.5f;
  else if (a < 2.5f)  q = 2.0f;
  else if (a < 3.5f)  q = 3.0f;
  else if (a < 5.0f)  q = 4.0f;
  else                q = 6.0f;
  return copysignf(q, v);
}

// round f (in [0,448]) to fp8 e4m3fn, RNE — exact pow2 arithmetic
static __device__ __forceinline__ float cvt_e4m3(float f) {
  if (f < 0.015625f) return rintf(f * 512.0f) * 0.001953125f;  // subnormal, q=2^-9
  int e = (int)(__float_as_uint(f) >> 23) - 127;
  float q = __uint_as_float((unsigned)(e - 3 + 127) << 23);    // 2^(e-3)
  return rintf(f / q) * q;                                     // exact div/mul by pow2
}

// ------- kernel 0: pack fp4-values-in-f32 to 4-bit codes (pure stream) -------
// 8,847,360 threads; thread i: read 8 f32 (32B), write 1 u32 of nibbles.
__global__ void k_wpack(const float* __restrict__ w, unsigned* __restrict__ wp) {
  int i = blockIdx.x * blockDim.x + threadIdx.x;
  const float4* p = (const float4*)w + 2 * (size_t)i;
  float4 a = p[0], b = p[1];
  float v[8] = {a.x, a.y, a.z, a.w, b.x, b.y, b.z, b.w};
  unsigned pk = 0;
#pragma unroll
  for (int j = 0; j < 8; ++j) {
    unsigned bits = __float_as_uint(v[j]);
    unsigned t = (bits >> 22) & 0x1FFu;                       // sign dropped
    unsigned idx = (t >= 0xFCu) ? (t - 0xFBu - (t >= 0xFEu)) : 0u;
    unsigned nib = idx | ((bits >> 28) & 8u);                 // sign -> bit3
    pk |= nib << (4 * j);
  }
  wp[i] = pk;
}

// ------- kernel 1: zero output (atomic target) + global amax of bf16(x) -------
__global__ void k_prep(const float* __restrict__ x, unsigned* __restrict__ amax_bits,
                       float4* __restrict__ out4) {
  int idx = blockIdx.x * blockDim.x + threadIdx.x;   // 327680 threads
#pragma unroll 1
  for (int j = idx; j < 884736; j += 327680) out4[j] = (float4){0.f, 0.f, 0.f, 0.f};
  float4 v = ((const float4*)x)[idx];                // exact cover of x
  float m = fmaxf(fmaxf(fabsf(bf16r(v.x)), fabsf(bf16r(v.y))),
                  fmaxf(fabsf(bf16r(v.z)), fabsf(bf16r(v.w))));
#pragma unroll
  for (int off = 32; off; off >>= 1) m = fmaxf(m, __shfl_xor(m, off));
  if ((threadIdx.x & 63) == 0) atomicMax(amax_bits, __float_as_uint(m));
}

// ------- kernel 2: activation nvfp4 quant, folded to bf16 a_u = q*s -------
__global__ void k_aquant(const float* __restrict__ x,
                         const unsigned* __restrict__ amax_bits,
                         __bf16* __restrict__ au) {
  int idx = blockIdx.x * blockDim.x + threadIdx.x;  // 0..81919 (m*320+b)
  int m = idx / NBLK;
  int b = idx - m * NBLK;
  float amax = __uint_as_float(*amax_bits);
  float gs  = 2688.0f / amax;   // (448*6)/amax, matches ref op order
  float gs6 = gs / 6.0f;
  const float4* xp = (const float4*)(x + m * K_TOT + b * 16);
  float4 v0 = xp[0], v1 = xp[1], v2 = xp[2], v3 = xp[3];
  float xv[16];
  xv[0]=bf16r(v0.x); xv[1]=bf16r(v0.y); xv[2]=bf16r(v0.z); xv[3]=bf16r(v0.w);
  xv[4]=bf16r(v1.x); xv[5]=bf16r(v1.y); xv[6]=bf16r(v1.z); xv[7]=bf16r(v1.w);
  xv[8]=bf16r(v2.x); xv[9]=bf16r(v2.y); xv[10]=bf16r(v2.z); xv[11]=bf16r(v2.w);
  xv[12]=bf16r(v3.x); xv[13]=bf16r(v3.y); xv[14]=bf16r(v3.z); xv[15]=bf16r(v3.w);
  float am = 0.f;
#pragma unroll
  for (int j = 0; j < 16; ++j) am = fmaxf(am, fabsf(xv[j]));
  float s = cvt_e4m3(fminf(am * gs6, 448.0f));
  float g = gs / ((s == 0.f) ? 1.f : s);
  bf16x8 p0, p1;
#pragma unroll
  for (int j = 0; j < 8; ++j) p0[j] = (__bf16)(fp4round(xv[j] * g) * s);      // exact in bf16
#pragma unroll
  for (int j = 0; j < 8; ++j) p1[j] = (__bf16)(fp4round(xv[8 + j] * g) * s);
  bf16x8* dst = (bf16x8*)(au + (size_t)idx * 16);
  dst[0] = p0; dst[1] = p1;
}

// ------- kernel 3: bf16 MFMA GEMM from PACKED weights, split-K (R3 structure) -------
// BM=256 (all M), BN=64, BK=64, 512 thr (8 waves: 4M x 2N), wave tile 64x32.
__global__ __launch_bounds__(512, 4) void k_gemm(
    const __bf16* __restrict__ au,      // [256][5120] bf16 (scales folded)
    const unsigned* __restrict__ wp,    // [N][640] packed fp4 codes
    const float*  __restrict__ wsc,     // [N][320] fp8-representable scales
    const unsigned* __restrict__ amax_bits,
    const float*  __restrict__ wgs,     // scalar
    const float*  __restrict__ bias,    // [N]
    float* __restrict__ out)            // [256][13824], pre-zeroed
{
  __shared__ __bf16 Ab[2][M_TOT * BK];  // 2 x 32 KB
  __shared__ __bf16 Bb[2][BN * BK];     // 2 x 8 KB

  const int tid  = threadIdx.x;
  const int lane = tid & 63;
  const int wv   = tid >> 6;     // 0..7
  const int wm   = wv >> 1;      // 0..3 (64-row group)
  const int wn   = wv & 1;       // 0..1 (32-col group)

  const int s     = blockIdx.x & (KSPLIT - 1);
  const int n0    = (blockIdx.x >> 2) * BN;
  const int kbase = s * KCH;

  // A staging: global_load_lds, linear LDS dest; source pre-swizzled so that
  // LDS holds layout byte = row*128 + (colbytes ^ ((row&7)<<4)).
  const int arow  = wv * 32 + (lane >> 3);           // + i*8 per call
  const int acolp = 8 * ((lane & 7) ^ (lane >> 3));  // pre-swizzled k offset

  // B staging: 1 packed u32 (8 weights) per thread per step + 1 scale
  const int brow = tid >> 3;    // 0..63
  const int bcg  = tid & 7;     // 8-elem col group
  const unsigned* wpp = wp + (size_t)(n0 + brow) * KPACK + (kbase >> 3) + bcg;
  const float*    wsp = wsc + (size_t)(n0 + brow) * NBLK + s * (KCH / 16) + (bcg >> 1);
  const int bdst = brow * 128 + ((bcg * 16) ^ ((brow & 7) << 4));

  // fragment read offsets
  const int sw    = (lane & 7) << 4;
  const int hi    = lane >> 4;
  const int r15   = lane & 15;

  floatx4 acc[4][2];
#pragma unroll
  for (int fm = 0; fm < 4; ++fm)
#pragma unroll
    for (int fn = 0; fn < 2; ++fn) acc[fm][fn] = (floatx4){0.f, 0.f, 0.f, 0.f};

  unsigned bpk; float bs;

  auto issueA = [&](int t, int buf) {
    const __bf16* src = au + (size_t)arow * K_TOT + kbase + t * BK + acolp;
    char* dst = (char*)(&Ab[buf][0]) + wv * 4096;
#pragma unroll
    for (int i = 0; i < 4; ++i)
      GLOAD_LDS16(src + (size_t)i * 8 * K_TOT, dst + i * 1024);
  };
  auto loadB = [&](int t) {
    bpk = wpp[t * 8];
    bs  = wsp[t * 4];
  };
  auto writeB = [&](int buf) {
    bf16x8 pkv;
#pragma unroll
    for (int j = 0; j < 8; ++j) {
      unsigned idx = (bpk >> (4 * j)) & 7u;
      unsigned sg  = (bpk >> (4 * j + 3)) & 1u;
      unsigned mb  = (idx == 0) ? 0u
                   : (idx == 1) ? 0x3F000000u
                                : 0x3F800000u + ((idx - 2u) << 22);
      float m = __uint_as_float(mb | (sg << 31));
      pkv[j] = (__bf16)(m * bs);                 // exact in bf16
    }
    *(bf16x8*)((char*)(&Bb[buf][0]) + bdst) = pkv;
  };
  auto compute = [&](int buf) {
    char* pA = (char*)(&Ab[buf][0]);
    char* pB = (char*)(&Bb[buf][0]);
#pragma unroll
    for (int ss = 0; ss < 2; ++ss) {
      const int cb = ss * 64 + hi * 16;
      bf16x8 af[4], bfr[2];
#pragma unroll
      for (int fm = 0; fm < 4; ++fm)
        af[fm] = *(const bf16x8*)(pA + (wm * 64 + fm * 16 + r15) * 128 + (cb ^ sw));
#pragma unroll
      for (int fn = 0; fn < 2; ++fn)
        bfr[fn] = *(const bf16x8*)(pB + (wn * 32 + fn * 16 + r15) * 128 + (cb ^ sw));
#pragma unroll
      for (int fm = 0; fm < 4; ++fm)
#pragma unroll
        for (int fn = 0; fn < 2; ++fn)
          acc[fm][fn] = __builtin_amdgcn_mfma_f32_16x16x32_bf16(af[fm], bfr[fn], acc[fm][fn], 0, 0, 0);
    }
  };

  // 2-phase pipeline
  int buf = 0;
  issueA(0, 0);
  loadB(0);
  writeB(0);
  __syncthreads();
#pragma unroll 1
  for (int t = 0; t < NSTEP; ++t) {
    if (t + 1 < NSTEP) { issueA(t + 1, buf ^ 1); loadB(t + 1); }
    compute(buf);
    if (t + 1 < NSTEP) writeB(buf ^ 1);
    __syncthreads();
    buf ^= 1;
  }

  // epilogue: atomic accumulate (out pre-zeroed; bias folded into split 0)
  float amax = __uint_as_float(*amax_bits);
  float a_gs = 2688.0f / amax;
  float alpha = 1.0f / (a_gs * wgs[0]);
#pragma unroll
  for (int fm = 0; fm < 4; ++fm) {
#pragma unroll
    for (int fn = 0; fn < 2; ++fn) {
      int mrow = wm * 64 + fm * 16 + hi * 4;
      int ncol = n0 + wn * 32 + fn * 16 + r15;
      float bb = (s == 0) ? bias[ncol] : 0.0f;
#pragma unroll
      for (int j = 0; j < 4; ++j)
        atomicAdd(&out[(size_t)(mrow + j) * N_TOT + ncol],
                  acc[fm][fn][j] * alpha + bb);
    }
  }
}

extern "C" void kernel_launch(void* const* d_in, const int* in_sizes, int n_in,
                              void* d_out, int out_size, void* d_ws, size_t ws_size,
                              hipStream_t stream) {
  const float* x    = (const float*)d_in[0];
  const float* wq   = (const float*)d_in[1];
  const float* wsc  = (const float*)d_in[2];
  const float* wgs  = (const float*)d_in[3];
  const float* bias = (const float*)d_in[4];
  float* out = (float*)d_out;

  unsigned* amax = (unsigned*)d_ws;
  __bf16* au = (__bf16*)((char*)d_ws + 256);                 // 2.62 MB
  unsigned* wpk = (unsigned*)((char*)d_ws + (4u << 20));     // 35.4 MB packed

  hipMemsetAsync(d_ws, 0, 4, stream);
  k_wpack<<<dim3(N_TOT * KPACK / 256), dim3(256), 0, stream>>>(wq, wpk);
  k_prep<<<dim3(1280), dim3(256), 0, stream>>>(x, amax, (float4*)out);
  k_aquant<<<dim3(M_TOT * NBLK / 256), dim3(256), 0, stream>>>(x, amax, au);
  k_gemm<<<dim3((N_TOT / BN) * KSPLIT), dim3(512), 0, stream>>>(au, wpk, wsc, amax, wgs, bias, out);
}